// Round 3
// baseline (880.280 us; speedup 1.0000x reference)
//
#include <hip/hip_runtime.h>
#include <hip/hip_bf16.h>
#include <cstdint>

// GCNModelVAE forward, fp32 accumulate, dtype-dual (bf16 OR f32 I/O).
//   G1: S1T[256,8192]  = (x @ Wh)^T
//   G2: H[8192,256]    = relu(adj @ S1)      (B = S1T, NT)
//   G3: TT[128,8192]   = (H @ [Wm|Wl])^T
//   G4: [zmean|zlog]   = adj @ T             (B = TT, NT) + bf16 ws copy of Zm
//   G5: recon          = Zm @ Zm^T           (A=B=ZmWS, NT)
//
// R2 post-mortem: structure audited correct, still NaN => the NaN is minted
// reading the inputs, i.e. dtype mismatch (reference is f32; test label says
// bf16). R3: runtime dtype detection + both pipelines launched, dead one
// early-exits on a ws flag. Intermediates always bf16 (MFMA), fp32 acc.

typedef __hip_bfloat16 hbf16;
typedef __bf16 bf16x8 __attribute__((ext_vector_type(8)));
typedef float  f32x4  __attribute__((ext_vector_type(4)));

#define N_NODES 8192
#define D_INF   512
#define D_HID   256
#define D_Z     64

enum { EPI_NORM = 0, EPI_RELU = 1, EPI_TRANS = 2, EPI_SPLIT = 3 };

__device__ __forceinline__ float tofloat(float v) { return v; }
__device__ __forceinline__ float tofloat(hbf16 v) { return __bfloat162float(v); }

__device__ __forceinline__ bf16x8 load8(const hbf16* p) {
    return *(const bf16x8*)p;
}
__device__ __forceinline__ bf16x8 load8(const float* p) {
    f32x4 f0 = *(const f32x4*)p;
    f32x4 f1 = *(const f32x4*)(p + 4);
    bf16x8 r;
    r[0] = (__bf16)f0[0]; r[1] = (__bf16)f0[1];
    r[2] = (__bf16)f0[2]; r[3] = (__bf16)f0[3];
    r[4] = (__bf16)f1[0]; r[5] = (__bf16)f1[1];
    r[6] = (__bf16)f1[2]; r[7] = (__bf16)f1[3];
    return r;
}

__device__ __forceinline__ void store1(float* p, float v) { *p = v; }
__device__ __forceinline__ void store1(hbf16* p, float v) { *p = __float2bfloat16(v); }

// Classify d_in[1] (adj, uniform[0,1)): bf16 data -> low u16 of each u32 word
// is a bf16 in [0,1): nonzero with top byte <= 0x3F (~100%). f32 data -> low
// u16 is random mantissa bits (~25% pass). Flag 1 = bf16.
__global__ void detect_dtype(const unsigned int* __restrict__ w, int* __restrict__ flag) {
    __shared__ int cnt;
    if (threadIdx.x == 0) cnt = 0;
    __syncthreads();
    int c = 0;
#pragma unroll
    for (int i = 0; i < 16; ++i) {
        unsigned int v = w[threadIdx.x * 16 + i];
        unsigned int lo = v & 0xFFFFu;
        if (lo != 0u && (lo >> 8) <= 0x3Fu) ++c;
    }
    atomicAdd(&cnt, c);
    __syncthreads();
    if (threadIdx.x == 0) *flag = (cnt > 2560) ? 1 : 0;   // of 4096 samples
}

// NT GEMM, 64x64 tile, BK=64, 4 waves (each 32x32 via 2x2 of 16x16x32 bf16
// MFMA). A: dtype TA; B: always bf16 (ws intermediates); out: TOUT.
template <int EPI, int PIPE, typename TA, typename TOUT>
__global__ __launch_bounds__(256)
void gemm_nt64(const int* __restrict__ flag,
               const TA* __restrict__ A, int lda,
               const hbf16* __restrict__ B, int ldb,
               TOUT* __restrict__ C0, TOUT* __restrict__ C1,
               hbf16* __restrict__ CWS, int ldc, int K)
{
    if ((*flag != 0) != (PIPE != 0)) return;   // uniform: dead pipeline exits

    __shared__ hbf16 As[64 * 64];
    __shared__ hbf16 Bs[64 * 64];

    const int tid  = threadIdx.x;
    const int lane = tid & 63;
    const int w    = tid >> 6;        // wave 0..3
    const int wm0  = (w >> 1) * 32;   // wave's 32x32 quadrant
    const int wn0  = (w & 1) * 32;

    const int m0 = blockIdx.y * 64;
    const int n0 = blockIdx.x * 64;

    // staging: 256 threads, each moves 8 elements from rows {srow, srow+32}
    const int srow = tid >> 3;            // 0..31
    const int scol = (tid & 7) * 8;       // element col

    const size_t a_base = (size_t)(m0 + srow) * lda + scol;
    const size_t b_base = (size_t)(n0 + srow) * ldb + scol;

    f32x4 acc[2][2];
#pragma unroll
    for (int i = 0; i < 2; ++i)
#pragma unroll
        for (int j = 0; j < 2; ++j)
            acc[i][j] = (f32x4){0.f, 0.f, 0.f, 0.f};

    const int mrow = lane & 15;          // fragment row within 16
    const int kq   = (lane >> 4) * 8;    // quad * 8 along K

    for (int k0 = 0; k0 < K; k0 += 64) {
        bf16x8 va0 = load8(A + a_base + k0);
        bf16x8 va1 = load8(A + a_base + (size_t)32 * lda + k0);
        bf16x8 vb0 = load8(B + b_base + k0);
        bf16x8 vb1 = load8(B + b_base + (size_t)32 * ldb + k0);

        __syncthreads();   // previous iter's ds_reads done before overwrite
        *(bf16x8*)&As[srow * 64 + scol]        = va0;
        *(bf16x8*)&As[(srow + 32) * 64 + scol] = va1;
        *(bf16x8*)&Bs[srow * 64 + scol]        = vb0;
        *(bf16x8*)&Bs[(srow + 32) * 64 + scol] = vb1;
        __syncthreads();   // staged

#pragma unroll
        for (int ks = 0; ks < 2; ++ks) {
            bf16x8 a0 = *(const bf16x8*)&As[(wm0 + mrow) * 64 + ks * 32 + kq];
            bf16x8 a1 = *(const bf16x8*)&As[(wm0 + 16 + mrow) * 64 + ks * 32 + kq];
            bf16x8 b0 = *(const bf16x8*)&Bs[(wn0 + mrow) * 64 + ks * 32 + kq];
            bf16x8 b1 = *(const bf16x8*)&Bs[(wn0 + 16 + mrow) * 64 + ks * 32 + kq];
            acc[0][0] = __builtin_amdgcn_mfma_f32_16x16x32_bf16(a0, b0, acc[0][0], 0, 0, 0);
            acc[0][1] = __builtin_amdgcn_mfma_f32_16x16x32_bf16(a0, b1, acc[0][1], 0, 0, 0);
            acc[1][0] = __builtin_amdgcn_mfma_f32_16x16x32_bf16(a1, b0, acc[1][0], 0, 0, 0);
            acc[1][1] = __builtin_amdgcn_mfma_f32_16x16x32_bf16(a1, b1, acc[1][1], 0, 0, 0);
        }
    }

    // epilogue: C/D layout col=lane&15, row=(lane>>4)*4+reg  [m89/m91]
    const int cn = lane & 15;
    const int rq = (lane >> 4) * 4;
#pragma unroll
    for (int mt = 0; mt < 2; ++mt)
#pragma unroll
        for (int nt = 0; nt < 2; ++nt)
#pragma unroll
            for (int r = 0; r < 4; ++r) {
                int row = m0 + wm0 + mt * 16 + rq + r;
                int col = n0 + wn0 + nt * 16 + cn;
                float v = acc[mt][nt][r];
                if (EPI == EPI_RELU) v = v > 0.f ? v : 0.f;
                if (EPI == EPI_TRANS) {
                    store1(&C0[(size_t)col * ldc + row], v);
                } else if (EPI == EPI_SPLIT) {
                    if (col < D_Z) {
                        store1(&C0[(size_t)row * D_Z + col], v);
                        CWS[(size_t)row * D_Z + col] = __float2bfloat16(v);
                    } else {
                        store1(&C1[(size_t)row * D_Z + (col - D_Z)], v);
                    }
                } else {
                    store1(&C0[(size_t)row * ldc + col], v);
                }
            }
}

// Wh[512,256] -> WhT[256,512] (bf16)
template <int PIPE, typename T>
__global__ void prep_whT(const int* __restrict__ flag,
                         const T* __restrict__ W, hbf16* __restrict__ WT) {
    if ((*flag != 0) != (PIPE != 0)) return;
    int o = blockIdx.x * 256 + threadIdx.x;   // 256*512 total
    int n = o >> 9;
    int k = o & 511;
    WT[o] = __float2bfloat16(tofloat(W[k * D_HID + n]));
}

// Wm[256,64], Wl[256,64] -> WcT[128,256] (bf16; rows 0..63 = Wm^T, 64..127 = Wl^T)
template <int PIPE, typename T>
__global__ void prep_wcT(const int* __restrict__ flag,
                         const T* __restrict__ Wm, const T* __restrict__ Wl,
                         hbf16* __restrict__ WcT) {
    if ((*flag != 0) != (PIPE != 0)) return;
    int o = blockIdx.x * 256 + threadIdx.x;   // 128*256 total
    int n = o >> 8;
    int k = o & 255;
    WcT[o] = __float2bfloat16(tofloat((n < D_Z) ? Wm[k * D_Z + n]
                                                : Wl[k * D_Z + (n - D_Z)]));
}

template <int PIPE, typename T>
static void launch_pipeline(void* const* d_in, void* d_out,
                            int* flag, hbf16* S1T, hbf16* H, hbf16* WhT,
                            hbf16* WcT, hbf16* TT, hbf16* ZmWS,
                            hipStream_t stream) {
    const T* x   = (const T*)d_in[0];
    const T* adj = (const T*)d_in[1];
    const T* Wh  = (const T*)d_in[2];
    const T* Wm  = (const T*)d_in[3];
    const T* Wl  = (const T*)d_in[4];

    T* recon = (T*)d_out;                              // [8192,8192]
    T* zmean = recon + (size_t)N_NODES * N_NODES;      // [8192,64]
    T* zlog  = zmean + (size_t)N_NODES * D_Z;          // [8192,64]

    prep_whT<PIPE, T><<<512, 256, 0, stream>>>(flag, Wh, WhT);
    prep_wcT<PIPE, T><<<128, 256, 0, stream>>>(flag, Wm, Wl, WcT);

    // G1: S1T = (x @ Wh)^T        M=8192 N=256 K=512
    gemm_nt64<EPI_TRANS, PIPE, T, hbf16>
        <<<dim3(D_HID / 64, N_NODES / 64), 256, 0, stream>>>(
        flag, x, D_INF, WhT, D_INF, S1T, (hbf16*)nullptr, (hbf16*)nullptr,
        N_NODES, D_INF);

    // G2: H = relu(adj @ S1)      M=8192 N=256 K=8192
    gemm_nt64<EPI_RELU, PIPE, T, hbf16>
        <<<dim3(D_HID / 64, N_NODES / 64), 256, 0, stream>>>(
        flag, adj, N_NODES, S1T, N_NODES, H, (hbf16*)nullptr, (hbf16*)nullptr,
        D_HID, N_NODES);

    // G3: TT = (H @ [Wm|Wl])^T    M=8192 N=128 K=256
    gemm_nt64<EPI_TRANS, PIPE, hbf16, hbf16>
        <<<dim3(2 * D_Z / 64, N_NODES / 64), 256, 0, stream>>>(
        flag, H, D_HID, WcT, D_HID, TT, (hbf16*)nullptr, (hbf16*)nullptr,
        N_NODES, D_HID);

    // G4: [zmean|zlog] = adj @ T  M=8192 N=128 K=8192  (+ bf16 ws copy of Zm)
    gemm_nt64<EPI_SPLIT, PIPE, T, T>
        <<<dim3(2 * D_Z / 64, N_NODES / 64), 256, 0, stream>>>(
        flag, adj, N_NODES, TT, N_NODES, zmean, zlog, ZmWS, D_Z, N_NODES);

    // G5: recon = Zm @ Zm^T       M=8192 N=8192 K=64
    gemm_nt64<EPI_NORM, PIPE, hbf16, T>
        <<<dim3(N_NODES / 64, N_NODES / 64), 256, 0, stream>>>(
        flag, ZmWS, D_Z, ZmWS, D_Z, recon, (T*)nullptr, (hbf16*)nullptr,
        N_NODES, D_Z);
}

extern "C" void kernel_launch(void* const* d_in, const int* in_sizes, int n_in,
                              void* d_out, int out_size, void* d_ws, size_t ws_size,
                              hipStream_t stream) {
    int*   flag = (int*)d_ws;
    hbf16* S1T  = (hbf16*)((char*)d_ws + 256);                  // [256,8192]  4 MB
    hbf16* H    = S1T + (size_t)D_HID * N_NODES;                // [8192,256]  4 MB
    hbf16* WhT  = H   + (size_t)N_NODES * D_HID;                // [256,512]
    hbf16* WcT  = WhT + (size_t)D_HID * D_INF;                  // [128,256]
    hbf16* TT   = WcT + (size_t)2 * D_Z * D_HID;                // [128,8192]  2 MB
    hbf16* ZmWS = TT  + (size_t)2 * D_Z * N_NODES;              // [8192,64]   1 MB

    detect_dtype<<<1, 256, 0, stream>>>((const unsigned int*)d_in[1], flag);

    launch_pipeline<1, hbf16>(d_in, d_out, flag, S1T, H, WhT, WcT, TT, ZmWS, stream);
    launch_pipeline<0, float>(d_in, d_out, flag, S1T, H, WhT, WcT, TT, ZmWS, stream);
}